// Round 13
// baseline (1378.670 us; speedup 1.0000x reference)
//
#include <hip/hip_runtime.h>
#include <hip/hip_bf16.h>

// ---------------------------------------------------------------------------
// Hypernetwork ResNet, bf16x3-split MFMA (fp32-equivalent precision).
// R13 (best-of-breed): stage 1 = unfused conv_s1 (pinned weights, at HBM
// floor). Stages 2/3 = block_fused whole-image single-LDS-buffer pairs:
//   stage 2: 512 threads (8 waves x 1 tile, balanced, 62KB -> 2blk/CU
//            = 16 waves/CU, stage-3's proven residency)
//   stage 3: 256 threads (4 waves, 38.4KB -> 4 blk/CU) - at MFMA floor.
// Residual read from global fp32 X in epilogue; T overwrites X interior in
// LDS (halos keep X zeros). i=6/i=12 transitions via conv_mfma/conv_s23.
// ---------------------------------------------------------------------------

typedef __attribute__((ext_vector_type(8))) short bf16x8;
typedef __attribute__((ext_vector_type(4))) float f32x4;
typedef __attribute__((ext_vector_type(16))) float f32x16;
typedef unsigned short ushort_t;

#define OFFS_LIST {0,1,2,3,4,5,6,7,8,9,10,11,12,14,18,22,26,30,34,38,42,46,50,54,58,66,82,98,114,130,146,162,178,194,210,226,242}
#define K_LIST    {1,1,1,1,1,1,1,1,1,1,1,1,1,2,2,2,2,2,2,2,2,2,2,2,2,4,4,4,4,4,4,4,4,4,4,4}
#define H_LIST    {1,1,1,1,1,1,1,1,1,1,1,1,2,2,2,2,2,2,2,2,2,2,2,2,4,4,4,4,4,4,4,4,4,4,4,4}
#define WOFF_LIST {0,2304,4608,6912,9216,11520,13824,16128,18432,20736,23040,25344,27648,32256,41472,50688,59904,69120,78336,87552,96768,105984,115200,124416,133632,152064,188928,225792,262656,299520,336384,373248,410112,446976,483840,520704}
#define CIN_LIST  {16,16,16,16,16,16,16,16,16,16,16,16,16,32,32,32,32,32,32,32,32,32,32,32,32,64,64,64,64,64,64,64,64,64,64,64}
#define COUT_LIST {16,16,16,16,16,16,16,16,16,16,16,16,32,32,32,32,32,32,32,32,32,32,32,32,64,64,64,64,64,64,64,64,64,64,64,64}
#define WFOFF_LIST {0,7680,15360,23040,30720,38400,46080,53760,61440,69120,76800,84480,92160,107520,139776,170496,201216,231936,262656,293376,324096,354816,385536,416256,446976,508416,637440,760320,883200,1006080,1128960,1251840,1374720,1497600,1620480,1743360}

__constant__ int d_offs[37]  = OFFS_LIST;
__constant__ int d_k[36]     = K_LIST;
__constant__ int d_hh[36]    = H_LIST;
__constant__ int d_woff[36]  = WOFF_LIST;
__constant__ int d_cin[36]   = CIN_LIST;
__constant__ int d_cout[36]  = COUT_LIST;
__constant__ int d_wfoff[36] = WFOFF_LIST;

__device__ inline void split3(float x, ushort_t& h, ushort_t& m, ushort_t& l) {
    unsigned xb = __float_as_uint(x);
    unsigned hb = (xb + 0x8000u) >> 16;
    float fh = __uint_as_float(hb << 16);
    float r = x - fh;
    unsigned mb = (__float_as_uint(r) + 0x8000u) >> 16;
    float fm = __uint_as_float(mb << 16);
    float r2 = r - fm;
    unsigned lb = (__float_as_uint(r2) + 0x8000u) >> 16;
    h = (ushort_t)hb; m = (ushort_t)mb; l = (ushort_t)lb;
}
__device__ inline float b2f(ushort_t u) { return __uint_as_float(((unsigned)u) << 16); }

// --- prep: BN scale/shift; shp13 = bnsh[14]+rb6; shp25 = bnsh[26]+rb12 ------
__global__ void prep(const float* __restrict__ g, const float* __restrict__ be,
                     const float* __restrict__ m, const float* __restrict__ v,
                     const float* __restrict__ rb6, const float* __restrict__ rb12,
                     float* __restrict__ sc, float* __restrict__ sh,
                     float* __restrict__ shp13, float* __restrict__ shp25) {
    int i = blockIdx.x * blockDim.x + threadIdx.x;
    if (i < 2368) {
        float s = g[i] * rsqrtf(v[i] + 1e-5f);
        sc[i] = s;
        sh[i] = be[i] - m[i] * s;
    } else if (i < 2368 + 32) {
        int c = i - 2368;
        int idx2 = 14 * 64 + c;
        float s = g[idx2] * rsqrtf(v[idx2] + 1e-5f);
        shp13[c] = be[idx2] - m[idx2] * s + rb6[c];
    } else if (i < 2400 + 64) {
        int c = i - 2400;
        int idx2 = 26 * 64 + c;
        float s = g[idx2] * rsqrtf(v[idx2] + 1e-5f);
        shp25[c] = be[idx2] - m[idx2] * s + rb12[c];
    }
}

// --- Hypernetwork: one block per z-row. Emits fp32 weights [tap][ci][co]. ---
__global__ void hyper_kernel(const float* __restrict__ z_all, const float* __restrict__ w2,
                             const float* __restrict__ b2, const float* __restrict__ w1,
                             const float* __restrict__ b1, const float* __restrict__ bnsc,
                             float* __restrict__ Wg) {
    int n = blockIdx.x;
    int tid = threadIdx.x;
    __shared__ float zrow[64];
    __shared__ float hin[1024];
    if (tid < 64) zrow[tid] = z_all[n * 64 + tid];
    __syncthreads();
    for (int mcol = tid; mcol < 1024; mcol += 256) {
        float acc = b2[mcol];
        #pragma unroll 8
        for (int d = 0; d < 64; ++d) acc += zrow[d] * w2[d * 1024 + mcol];
        hin[mcol] = acc;
    }
    __syncthreads();
    int L = 0;
    while (n >= d_offs[L + 1]) ++L;
    int r = n - d_offs[L];
    int kk = d_k[L];
    int a = r / kk, bb = r % kk;
    int Cin = kk * 16;
    int Cout = d_hh[L] * 16;
    const float* scp = bnsc + (L + 1) * 64;
    float* wp = Wg + d_woff[L];
    for (int e = tid; e < 2304; e += 256) {
        int i = e / 144, o = e % 144;
        int j = o / 9, tap = o % 9;
        float acc = b1[o];
        #pragma unroll 8
        for (int d = 0; d < 64; ++d) acc += hin[i * 64 + d] * w1[d * 144 + o];
        int co = a * 16 + i;
        acc *= scp[co];
        wp[(tap * Cin + (bb * 16 + j)) * Cout + co] = acc;
    }
}

// --- split weights into bf16x3 fragment blocks ------------------------------
__global__ void split_w(const float* __restrict__ Wg, const float* __restrict__ rw6,
                        const float* __restrict__ rw12, ushort_t* __restrict__ Wf) {
    int L = blockIdx.y;
    int CIN = d_cin[L], COUT = d_cout[L];
    int idx = blockIdx.x * 256 + threadIdx.x;
    int j = idx & 7, lane = (idx >> 3) & 63, t = idx >> 9;
    int hi = lane >> 5;
    float wv;
    int base;
    if (L < 13) {                       // 16x16x32 fragment format
        int K = 9 * CIN, NKS = (K + 31) / 32, NT = COUT / 16;
        if (t >= NKS * NT) return;
        int nt = t % NT, ks = t / NT;
        int k = ks * 32 + (lane >> 4) * 8 + j;
        int co = nt * 16 + (lane & 15);
        wv = (k < K) ? Wg[d_woff[L] + k * COUT + co] : 0.f;
        base = d_wfoff[L] + ((ks * NT + nt) * 3) * 512 + lane * 8 + j;
    } else {                            // 32x32x16, padded taps (10), tap-inner
        int CG8 = CIN / 8, NKS = 5 * CG8, NT = COUT / 32;
        int TKS = NKS + ((L == 25) ? 2 : ((L == 13) ? 1 : 0));
        if (t >= TKS * NT) return;
        int nt = t % NT, ks = t / NT;
        int co = nt * 32 + (lane & 31);
        if (ks < NKS) {
            int o = 2 * ks + hi, tap = o % 10, c8 = o / 10;
            int ci = c8 * 8 + j;
            wv = (tap < 9) ? Wg[d_woff[L] + (tap * CIN + ci) * COUT + co] : 0.f;
        } else if (L == 25) {           // appended 1x1-s2 residual (32->64)
            int k = (ks - NKS) * 16 + hi * 8 + j;
            wv = rw12[co * 32 + k];
        } else {                        // L13 appended 1x1-s2 residual (16->32)
            int k = hi * 8 + j;
            wv = rw6[co * 16 + k];
        }
        base = d_wfoff[L] + ((ks * NT + nt) * 3) * 512 + lane * 8 + j;
    }
    ushort_t h, m, l;
    split3(wv, h, m, l);
    Wf[base] = h; Wf[base + 512] = m; Wf[base + 1024] = l;
}

// --- First conv: 3->16, NCHW in -> NHWC fp32 out ----------------------------
__global__ void conv_first(const float* __restrict__ x, const float* __restrict__ cw,
                           const float* __restrict__ cb, const float* __restrict__ g,
                           const float* __restrict__ be, const float* __restrict__ m,
                           const float* __restrict__ v, float* __restrict__ out) {
    int idx = blockIdx.x * 256 + threadIdx.x;
    int px = idx & 31; int t = idx >> 5;
    int py = t & 31;   int b = t >> 5;
    float acc[16];
    #pragma unroll
    for (int co = 0; co < 16; ++co) acc[co] = 0.f;
    const float* ip = x + (long)b * 3 * 1024;
    #pragma unroll 1
    for (int ci = 0; ci < 3; ++ci) {
        #pragma unroll 1
        for (int ky = 0; ky < 3; ++ky) {
            int iy = py + ky - 1;
            if ((unsigned)iy >= 32u) continue;
            #pragma unroll
            for (int kx = 0; kx < 3; ++kx) {
                int ix = px + kx - 1;
                if ((unsigned)ix < 32u) {
                    float xv = ip[ci * 1024 + iy * 32 + ix];
                    #pragma unroll
                    for (int co = 0; co < 16; ++co)
                        acc[co] += xv * cw[co * 27 + ci * 9 + ky * 3 + kx];
                }
            }
        }
    }
    long o = ((long)(b * 32 + py) * 32 + px) * 16;
    #pragma unroll
    for (int co = 0; co < 16; ++co) {
        float s = g[co] * rsqrtf(v[co] + 1e-5f);
        float val = (acc[co] + cb[co] - m[co]) * s + be[co];
        out[o + co] = fmaxf(val, 0.f);
    }
}

// --- zero the halo ring of a padded fp32 NHWC buffer ------------------------
__global__ void pad_zero_f32(float* __restrict__ buf, int H2, int C4) {
    int idx = blockIdx.x * 256 + threadIdx.x;
    int nb = 2 * H2 + 2 * (H2 - 2);
    int total = 1024 * nb * C4;
    if (idx >= total) return;
    int ch = idx % C4; int t = idx / C4;
    int bp = t % nb; int img = t / nb;
    int y, x;
    if (bp < H2) { y = 0; x = bp; }
    else if (bp < 2 * H2) { y = H2 - 1; x = bp - H2; }
    else { int s = bp - 2 * H2; y = 1 + (s >> 1); x = (s & 1) ? H2 - 1 : 0; }
    long off = (((long)img * H2 + y) * H2 + x) * (C4 * 4) + ch * 4;
    *(float4*)(buf + off) = make_float4(0.f, 0.f, 0.f, 0.f);
}

// --- Stage-1 conv_s1 (unfused): CIN=COUT=16, H=32, unpadded fp32 NHWC -------
template<int MODE>
__global__ __launch_bounds__(256) void conv_s1(
        const float* __restrict__ in, const ushort_t* __restrict__ wf,
        const float* __restrict__ shp, const float* __restrict__ res,
        float* __restrict__ out) {
    constexpr int W2 = 34, SLABPIX = 10 * W2;
    constexpr int NKS = 5;

    __shared__ uint4 lds[6 * SLABPIX];

    int tid = threadIdx.x, lane = tid & 63, wid = tid >> 6;
    int g = lane >> 4, r16 = lane & 15;
    int bid = blockIdx.x;
    int img = bid >> 2, blocky = bid & 3;
    int row0 = blocky * 8;

    const ushort_t* wfl = wf + lane * 8;
    bf16x8 wv[NKS][3];
    #pragma unroll
    for (int ks = 0; ks < NKS; ++ks)
        #pragma unroll
        for (int p = 0; p < 3; ++p)
            wv[ks][p] = *(const bf16x8*)(wfl + (ks * 3 + p) * 512);
    #pragma unroll
    for (int ks = 0; ks < NKS; ++ks)
        #pragma unroll
        for (int p = 0; p < 3; ++p)
            asm volatile("" : "+v"(wv[ks][p]));

    const float* ib = in + (long)img * (32 * 32 * 16);
    for (int it = tid; it < SLABPIX * 2; it += 256) {
        int pix = it % SLABPIX, cc = it / SLABPIX;
        int sr = pix / W2, sc = pix % W2;
        int gy = row0 - 1 + sr, gx = sc - 1;
        float vv[8];
        if ((unsigned)gy < 32u && (unsigned)gx < 32u) {
            const float4* p4 = (const float4*)(ib + ((long)gy * 32 + gx) * 16 + cc * 8);
            float4 a0 = p4[0], a1 = p4[1];
            vv[0]=a0.x; vv[1]=a0.y; vv[2]=a0.z; vv[3]=a0.w;
            vv[4]=a1.x; vv[5]=a1.y; vv[6]=a1.z; vv[7]=a1.w;
        } else {
            #pragma unroll
            for (int q = 0; q < 8; ++q) vv[q] = 0.f;
        }
        union { ushort_t u[8]; uint4 q; } H, M, L;
        #pragma unroll
        for (int q = 0; q < 8; ++q) split3(vv[q], H.u[q], M.u[q], L.u[q]);
        lds[(cc * 3 + 0) * SLABPIX + pix] = H.q;
        lds[(cc * 3 + 1) * SLABPIX + pix] = M.q;
        lds[(cc * 3 + 2) * SLABPIX + pix] = L.q;
    }
    __syncthreads();

    int pbase[4];
    #pragma unroll
    for (int mt = 0; mt < 4; ++mt) {
        int pid = (wid * 4 + mt) * 16 + r16;
        pbase[mt] = (pid >> 5) * W2 + (pid & 31);
    }

    f32x4 acc[4] = {};

    #pragma unroll
    for (int ks = 0; ks < NKS; ++ks) {
        int k0 = ks * 32 + g * 8;
        int tap = k0 >> 4;
        int ci8 = (k0 >> 3) & 1;
        int ky = (tap * 11) >> 5;
        int kx = tap - 3 * ky;
        bool dead = (ks == NKS - 1) && (g >= 2);
        int ofs = dead ? 0 : (ci8 * 3) * SLABPIX + ky * W2 + kx;
        #pragma unroll
        for (int mt = 0; mt < 4; ++mt) {
            int e16 = dead ? 0 : ofs + pbase[mt];
            bf16x8 ah = *(const bf16x8*)&lds[e16];
            bf16x8 am = *(const bf16x8*)&lds[e16 + SLABPIX];
            bf16x8 al = *(const bf16x8*)&lds[e16 + 2 * SLABPIX];
            f32x4 c = acc[mt];
            c = __builtin_amdgcn_mfma_f32_16x16x32_bf16(ah, wv[ks][0], c, 0, 0, 0);
            c = __builtin_amdgcn_mfma_f32_16x16x32_bf16(ah, wv[ks][1], c, 0, 0, 0);
            c = __builtin_amdgcn_mfma_f32_16x16x32_bf16(am, wv[ks][0], c, 0, 0, 0);
            c = __builtin_amdgcn_mfma_f32_16x16x32_bf16(ah, wv[ks][2], c, 0, 0, 0);
            c = __builtin_amdgcn_mfma_f32_16x16x32_bf16(am, wv[ks][1], c, 0, 0, 0);
            c = __builtin_amdgcn_mfma_f32_16x16x32_bf16(al, wv[ks][0], c, 0, 0, 0);
            acc[mt] = c;
        }
    }

    #pragma unroll
    for (int mt = 0; mt < 4; ++mt) {
        #pragma unroll
        for (int reg = 0; reg < 4; ++reg) {
            int pid = (wid * 4 + mt) * 16 + g * 4 + reg;
            int gy = row0 + (pid >> 5), gx = pid & 31;
            long oidx = (((long)img * 32 + gy) * 32 + gx) * 16 + r16;
            float val = acc[mt][reg] + shp[r16];
            if (MODE == 1) val += res[oidx];
            out[oidx] = fmaxf(val, 0.f);
        }
    }
}

// --- conv_mfma (i=6 conv1 only): 16x16x32 MFMA, LDS bf16x3 ------------------
template<int CIN, int COUT, int HIN, int STRIDE, int TH, int TW, int OUTF>
__global__ __launch_bounds__(256) void conv_mfma(
        const float* __restrict__ in, const ushort_t* __restrict__ wf,
        const float* __restrict__ shp, float* __restrict__ out) {
    constexpr int HOUT = HIN / STRIDE;
    constexpr int H2O = HOUT + 2;
    constexpr int CG8 = CIN / 8;
    constexpr int IH = (TH - 1) * STRIDE + 3;
    constexpr int IW = (TW - 1) * STRIDE + 3;
    constexpr int K = 9 * CIN;
    constexpr int NKS = (K + 31) / 32;
    constexpr bool TAIL = (K % 32) != 0;
    constexpr int NT = COUT / 16;
    constexpr int MTW = TH * TW / 64;
    constexpr int PADC = ((2 - (IH * IW)) % 8 + 8) % 8;
    constexpr int CSTU = IH * IW + PADC;
    constexpr int PST = CG8 * CSTU;
    constexpr int TX = HOUT / TW, TY = HOUT / TH;

    __shared__ uint4 lds[3 * PST];

    int tid = threadIdx.x;
    int bid = blockIdx.x;
    int tile = bid % (TY * TX);
    int b = bid / (TY * TX);
    int ty = tile / TX, tx = tile % TX;
    int Y0 = ty * TH, X0 = tx * TW;
    int gy0 = Y0 * STRIDE - 1, gx0 = X0 * STRIDE - 1;

    for (int e = tid; e < CG8 * IH * IW; e += 256) {
        int c8 = e / (IH * IW); int rr = e % (IH * IW);
        int ly = rr / IW, lx = rr % IW;
        int gy = gy0 + ly, gx = gx0 + lx;
        float vv[8];
        if ((unsigned)gy < (unsigned)HIN && (unsigned)gx < (unsigned)HIN) {
            const float4* p = (const float4*)(in + ((long)(b * HIN + gy) * HIN + gx) * CIN + c8 * 8);
            float4 a0 = p[0], a1 = p[1];
            vv[0]=a0.x; vv[1]=a0.y; vv[2]=a0.z; vv[3]=a0.w;
            vv[4]=a1.x; vv[5]=a1.y; vv[6]=a1.z; vv[7]=a1.w;
        } else {
            #pragma unroll
            for (int q = 0; q < 8; ++q) vv[q] = 0.f;
        }
        union { ushort_t u[8]; uint4 q4; } H, M, L;
        #pragma unroll
        for (int q = 0; q < 8; ++q) split3(vv[q], H.u[q], M.u[q], L.u[q]);
        int a16 = c8 * CSTU + rr;
        lds[a16] = H.q4; lds[PST + a16] = M.q4; lds[2 * PST + a16] = L.q4;
    }
    __syncthreads();

    int lane = tid & 63, wid = tid >> 6;
    int g = lane >> 4, r16 = lane & 15;

    f32x4 acc[MTW][NT] = {};

    int pbase[MTW];
    #pragma unroll
    for (int mt = 0; mt < MTW; ++mt) {
        int pid = (wid + 4 * mt) * 16 + r16;
        int py = pid / TW, px = pid % TW;
        pbase[mt] = (py * STRIDE) * IW + px * STRIDE;
    }

    #pragma unroll
    for (int ks = 0; ks < NKS; ++ks) {
        bf16x8 bfr[NT][3];
        #pragma unroll
        for (int nt = 0; nt < NT; ++nt)
            #pragma unroll
            for (int p = 0; p < 3; ++p)
                bfr[nt][p] = *(const bf16x8*)(wf + ((ks * NT + nt) * 3 + p) * 512 + lane * 8);

        int k0 = ks * 32 + g * 8;
        int tap = k0 / CIN;
        int ci8 = (k0 % CIN) >> 3;
        int ky = (tap * 11) >> 5;
        int kx = tap - 3 * ky;
        int ofs = ci8 * CSTU + ky * IW + kx;

        #pragma unroll
        for (int mt = 0; mt < MTW; ++mt) {
            int e16 = ofs + pbase[mt];
            if (TAIL && ks == NKS - 1) e16 = (g < 2) ? e16 : 0;
            const uint4* ap = lds + e16;
            bf16x8 ah = *(const bf16x8*)(ap);
            bf16x8 am = *(const bf16x8*)(ap + PST);
            bf16x8 al = *(const bf16x8*)(ap + 2 * PST);
            #pragma unroll
            for (int nt = 0; nt < NT; ++nt) {
                f32x4 c = acc[mt][nt];
                c = __builtin_amdgcn_mfma_f32_16x16x32_bf16(ah, bfr[nt][0], c, 0, 0, 0);
                c = __builtin_amdgcn_mfma_f32_16x16x32_bf16(ah, bfr[nt][1], c, 0, 0, 0);
                c = __builtin_amdgcn_mfma_f32_16x16x32_bf16(am, bfr[nt][0], c, 0, 0, 0);
                c = __builtin_amdgcn_mfma_f32_16x16x32_bf16(ah, bfr[nt][2], c, 0, 0, 0);
                c = __builtin_amdgcn_mfma_f32_16x16x32_bf16(am, bfr[nt][1], c, 0, 0, 0);
                c = __builtin_amdgcn_mfma_f32_16x16x32_bf16(al, bfr[nt][0], c, 0, 0, 0);
                acc[mt][nt] = c;
            }
        }
    }

    #pragma unroll
    for (int mt = 0; mt < MTW; ++mt) {
        #pragma unroll
        for (int nt = 0; nt < NT; ++nt) {
            int co = nt * 16 + r16;
            float shv = shp[co];
            #pragma unroll
            for (int reg = 0; reg < 4; ++reg) {
                int pid = (wid + 4 * mt) * 16 + g * 4 + reg;
                int py = pid / TW, px = pid % TW;
                int gy = Y0 + py, gx = X0 + px;
                float val = fmaxf(acc[mt][nt][reg] + shv, 0.f);
                if (OUTF == 0) {
                    out[((long)(b * HOUT + gy) * HOUT + gx) * COUT + co] = val;
                } else {
                    out[(((long)b * H2O + gy + 1) * H2O + gx + 1) * COUT + co] = val;
                }
            }
        }
    }
}

// --- conv_s23: LDS-slab conv, 32x32x16 MFMA, padded fp32 NHWC io ------------
template<int CIN, int COUT, int HIN, int STRIDE, int PXB, int MODE, int RKS, int CHUNK>
__global__ __launch_bounds__(256) void conv_s23(
        const float* __restrict__ in, const ushort_t* __restrict__ wf,
        const float* __restrict__ shp, const float* __restrict__ res,
        float* __restrict__ out) {
    constexpr int HOUT = HIN / STRIDE;
    constexpr int H2I = HIN + 2, H2O = HOUT + 2;
    constexpr int C8 = CIN / 8;
    constexpr int NKS = 5 * C8;
    constexpr int TKS = NKS + RKS;
    constexpr int NC = TKS / CHUNK;
    constexpr int NTT = COUT / 32;
    constexpr int ROWSB = PXB / HOUT;
    constexpr int SLABR = (ROWSB - 1) * STRIDE + 3;
    constexpr int SLABPIX = SLABR * H2I;
    constexpr int NBLK = HOUT / ROWSB;
    constexpr int RESU = 3 * C8 * SLABPIX;
    constexpr int LDSU = RESU + ((MODE == 2 || MODE == 3) ? 768 : 0);

    __shared__ uint4 lds[LDSU];

    int tid = threadIdx.x, lane = tid & 63, wid = tid >> 6;
    int lp = lane & 31, hi = lane >> 5;
    int bid = blockIdx.x;
    int img = bid / NBLK, blocky = bid % NBLK;
    int pxg = wid / NTT, ntb = wid % NTT;
    int pix0 = pxg * 32 + lp;
    int py_blk = pix0 / HOUT, px = pix0 % HOUT;
    int py = blocky * ROWSB + py_blk;
    int slabrow0 = blocky * ROWSB * STRIDE;

    const ushort_t* wfl = wf + lane * 8;

    bf16x8 wA[CHUNK][3], wB[CHUNK][3];
    auto LW = [&](int c, bf16x8 (&w)[CHUNK][3]) {
        #pragma unroll
        for (int i = 0; i < CHUNK; ++i) {
            int ks = c * CHUNK + i;
            #pragma unroll
            for (int pp = 0; pp < 3; ++pp)
                w[i][pp] = *(const bf16x8*)(wfl + ((ks * NTT + ntb) * 3 + pp) * 512);
        }
    };

    LW(0, wA);
    if (NC > 1) LW(1, wB);

    const float* ib = in + (long)img * H2I * H2I * CIN;
    for (int it = tid; it < SLABPIX * C8; it += 256) {
        int pix = it % SLABPIX, cc = it / SLABPIX;
        int sr = pix / H2I, sc = pix % H2I;
        const float* p4 = ib + ((long)(slabrow0 + sr) * H2I + sc) * CIN + cc * 8;
        float4 a0 = ((const float4*)p4)[0], a1 = ((const float4*)p4)[1];
        float vv[8] = {a0.x, a0.y, a0.z, a0.w, a1.x, a1.y, a1.z, a1.w};
        union { ushort_t u[8]; uint4 q; } H, M, L;
        #pragma unroll
        for (int q = 0; q < 8; ++q) split3(vv[q], H.u[q], M.u[q], L.u[q]);
        int u0 = cc * 3;
        lds[u0 * SLABPIX + pix] = H.q;
        lds[(u0 + 1) * SLABPIX + pix] = M.q;
        lds[(u0 + 2) * SLABPIX + pix] = L.q;
    }
    if (MODE == 2) {
        for (int it = tid; it < 256; it += 256) {
            int pix = it & 63, cc = it >> 6;
            int ry = pix >> 3, rx = pix & 7;
            const float* r4 = res + (((long)img * 18 + (2 * ry + 1)) * 18 + (2 * rx + 1)) * 32 + cc * 8;
            float4 a0 = ((const float4*)r4)[0], a1 = ((const float4*)r4)[1];
            float vv[8] = {a0.x, a0.y, a0.z, a0.w, a1.x, a1.y, a1.z, a1.w};
            union { ushort_t u[8]; uint4 q; } H, M, L;
            #pragma unroll
            for (int q = 0; q < 8; ++q) split3(vv[q], H.u[q], M.u[q], L.u[q]);
            int u0 = RESU + cc * 3 * 64;
            lds[u0 + pix] = H.q;
            lds[u0 + 64 + pix] = M.q;
            lds[u0 + 128 + pix] = L.q;
        }
    }
    if (MODE == 3) {
        for (int it = tid; it < 256; it += 256) {
            int opix = it >> 1, cg = it & 1;
            int r = opix / 16, cxx = opix % 16;
            int gy = (blocky * 8 + r) * 2, gx = cxx * 2;
            const float* r4 = res + (((long)img * 32 + gy) * 32 + gx) * 16 + cg * 8;
            float4 a0 = ((const float4*)r4)[0], a1 = ((const float4*)r4)[1];
            float vv[8] = {a0.x, a0.y, a0.z, a0.w, a1.x, a1.y, a1.z, a1.w};
            union { ushort_t u[8]; uint4 q; } H, M, L;
            #pragma unroll
            for (int q = 0; q < 8; ++q) split3(vv[q], H.u[q], M.u[q], L.u[q]);
            int u0 = RESU + opix * 6;
            lds[u0 + cg] = H.q;
            lds[u0 + 2 + cg] = M.q;
            lds[u0 + 4 + cg] = L.q;
        }
    }
    __syncthreads();

    int pbase = (py_blk * STRIDE) * H2I + px * STRIDE;
    f32x16 acc = {};

    auto DOC = [&](int c, bf16x8 (&w)[CHUNK][3]) {
        #pragma unroll
        for (int i = 0; i < CHUNK; ++i) {
            int ks = c * CHUNK + i;
            bf16x8 x0, x1, x2;
            if (RKS > 0 && ks >= NKS) {
                if (MODE == 2) {
                    int o2 = 2 * (ks - NKS) + hi;
                    int a = RESU + o2 * 3 * 64 + pix0;
                    x0 = *(const bf16x8*)&lds[a];
                    x1 = *(const bf16x8*)&lds[a + 64];
                    x2 = *(const bf16x8*)&lds[a + 128];
                } else {
                    int a = RESU + pix0 * 6 + hi;
                    x0 = *(const bf16x8*)&lds[a];
                    x1 = *(const bf16x8*)&lds[a + 2];
                    x2 = *(const bf16x8*)&lds[a + 4];
                }
            } else {
                int o = 2 * ks + hi;
                int tap = o % 10, c8i = o / 10;
                int ky = (tap * 11) >> 5, kx = tap - 3 * ky;
                int t16 = (tap == 9) ? 0 : (ky * H2I + kx);
                int a = (c8i * 3) * SLABPIX + pbase + t16;
                x0 = *(const bf16x8*)&lds[a];
                x1 = *(const bf16x8*)&lds[a + SLABPIX];
                x2 = *(const bf16x8*)&lds[a + 2 * SLABPIX];
            }
            acc = __builtin_amdgcn_mfma_f32_32x32x16_bf16(w[i][0], x0, acc, 0, 0, 0);
            acc = __builtin_amdgcn_mfma_f32_32x32x16_bf16(w[i][1], x0, acc, 0, 0, 0);
            acc = __builtin_amdgcn_mfma_f32_32x32x16_bf16(w[i][0], x1, acc, 0, 0, 0);
            acc = __builtin_amdgcn_mfma_f32_32x32x16_bf16(w[i][2], x0, acc, 0, 0, 0);
            acc = __builtin_amdgcn_mfma_f32_32x32x16_bf16(w[i][1], x1, acc, 0, 0, 0);
            acc = __builtin_amdgcn_mfma_f32_32x32x16_bf16(w[i][0], x2, acc, 0, 0, 0);
        }
    };

    #pragma unroll 1
    for (int c = 0; c < NC; c += 2) {
        DOC(c, wA);
        if (c + 2 < NC) LW(c + 2, wA);
        if (c + 1 < NC) { DOC(c + 1, wB); if (c + 3 < NC) LW(c + 3, wB); }
    }

    float* ob = out + (((long)img * H2O + py + 1) * H2O + (px + 1)) * COUT;
    #pragma unroll
    for (int g = 0; g < 4; ++g) {
        int co = ntb * 32 + g * 8 + 4 * hi;
        float v0 = acc[4 * g + 0] + shp[co + 0];
        float v1 = acc[4 * g + 1] + shp[co + 1];
        float v2 = acc[4 * g + 2] + shp[co + 2];
        float v3 = acc[4 * g + 3] + shp[co + 3];
        *(float4*)(ob + co) = make_float4(fmaxf(v0, 0.f), fmaxf(v1, 0.f),
                                          fmaxf(v2, 0.f), fmaxf(v3, 0.f));
    }
}

// --- block_fused: whole residual pair, one image per block ------------------
// BLK threads (BLK/64 waves). Single LDS buffer: X bf16x3 planes; conv1
// reads X; T overwrites X interior (halo stays zero); conv2 reads T;
// residual from global fp32 X in epilogue.
template<int CIN, int HIN, int TPW, int BLK>
__global__ __launch_bounds__(BLK) void block_fused(
        const float* __restrict__ in, const ushort_t* __restrict__ wf1,
        const ushort_t* __restrict__ wf2, const float* __restrict__ sh1,
        const float* __restrict__ sh2, float* __restrict__ out) {
    constexpr int H2 = HIN + 2, H2PIX = H2 * H2;
    constexpr int C8 = CIN / 8;
    constexpr int NKS = 5 * C8;
    constexpr int CHUNK = 5, NC = NKS / CHUNK;
    constexpr int NTT = CIN / 32;
    constexpr int BUFU = 3 * C8 * H2PIX;

    __shared__ uint4 lds[BUFU];
    ushort_t* lsh = (ushort_t*)lds;

    int tid = threadIdx.x, lane = tid & 63, wid = tid >> 6;
    int lp = lane & 31, hi = lane >> 5;
    int img = blockIdx.x;

    int ntb0 = (wid * TPW) % NTT;
    int pb[TPW];
    #pragma unroll
    for (int t = 0; t < TPW; ++t) {
        int tl = wid * TPW + t;
        int pix = (tl / NTT) * 32 + lp;
        pb[t] = (pix / HIN + 1) * H2 + (pix % HIN + 1);
    }

    const float* ib = in + (long)img * H2PIX * CIN;
    for (int it = tid; it < H2PIX * C8; it += BLK) {
        int cc = it % C8, pix = it / C8;
        const float4* p4 = (const float4*)(ib + (long)pix * CIN + cc * 8);
        float4 a0 = p4[0], a1 = p4[1];
        float vv[8] = {a0.x, a0.y, a0.z, a0.w, a1.x, a1.y, a1.z, a1.w};
        union { ushort_t u[8]; uint4 q; } H, M, L;
        #pragma unroll
        for (int q = 0; q < 8; ++q) split3(vv[q], H.u[q], M.u[q], L.u[q]);
        lds[(cc * 3 + 0) * H2PIX + pix] = H.q;
        lds[(cc * 3 + 1) * H2PIX + pix] = M.q;
        lds[(cc * 3 + 2) * H2PIX + pix] = L.q;
    }
    __syncthreads();

    bf16x8 wA[CHUNK][3], wB[CHUNK][3];
    f32x16 acc[TPW];

    auto CONV = [&](const ushort_t* wf) {
        const ushort_t* wfl = wf + lane * 8;
        #pragma unroll
        for (int t = 0; t < TPW; ++t)
            #pragma unroll
            for (int q = 0; q < 16; ++q) acc[t][q] = 0.f;
        auto LW = [&](int c, bf16x8 (&w)[CHUNK][3]) {
            #pragma unroll
            for (int i = 0; i < CHUNK; ++i) {
                int ks = c * CHUNK + i;
                #pragma unroll
                for (int pp = 0; pp < 3; ++pp)
                    w[i][pp] = *(const bf16x8*)(wfl + ((ks * NTT + ntb0) * 3 + pp) * 512);
            }
        };
        auto DOC = [&](int c, bf16x8 (&w)[CHUNK][3]) {
            #pragma unroll
            for (int i = 0; i < CHUNK; ++i) {
                int ks = c * CHUNK + i;
                int o = 2 * ks + hi;
                int tap = o % 10, c8i = o / 10;
                int ky = (tap * 11) >> 5, kx = tap - 3 * ky;
                int rel = (tap == 9) ? 0 : (ky - 1) * H2 + (kx - 1);
                #pragma unroll
                for (int t = 0; t < TPW; ++t) {
                    int a = (tap == 9) ? (c8i * 3) * H2PIX
                                       : (c8i * 3) * H2PIX + pb[t] + rel;
                    bf16x8 x0 = *(const bf16x8*)&lds[a];
                    bf16x8 x1 = *(const bf16x8*)&lds[a + H2PIX];
                    bf16x8 x2 = *(const bf16x8*)&lds[a + 2 * H2PIX];
                    f32x16 c2 = acc[t];
                    c2 = __builtin_amdgcn_mfma_f32_32x32x16_bf16(w[i][0], x0, c2, 0, 0, 0);
                    c2 = __builtin_amdgcn_mfma_f32_32x32x16_bf16(w[i][1], x0, c2, 0, 0, 0);
                    c2 = __builtin_amdgcn_mfma_f32_32x32x16_bf16(w[i][0], x1, c2, 0, 0, 0);
                    c2 = __builtin_amdgcn_mfma_f32_32x32x16_bf16(w[i][2], x0, c2, 0, 0, 0);
                    c2 = __builtin_amdgcn_mfma_f32_32x32x16_bf16(w[i][1], x1, c2, 0, 0, 0);
                    c2 = __builtin_amdgcn_mfma_f32_32x32x16_bf16(w[i][0], x2, c2, 0, 0, 0);
                    acc[t] = c2;
                }
            }
        };
        LW(0, wA);
        if (NC > 1) LW(1, wB);
        #pragma unroll 1
        for (int c = 0; c < NC; c += 2) {
            DOC(c, wA);
            if (c + 2 < NC) LW(c + 2, wA);
            if (c + 1 < NC) { DOC(c + 1, wB); if (c + 3 < NC) LW(c + 3, wB); }
        }
    };

    CONV(wf1);
    __syncthreads();
    #pragma unroll
    for (int t = 0; t < TPW; ++t) {
        #pragma unroll
        for (int q = 0; q < 4; ++q) {
            int co = ntb0 * 32 + q * 8 + 4 * hi;
            int c8o = co >> 3;
            ushort4 h4, m4, l4;
            #pragma unroll
            for (int e = 0; e < 4; ++e) {
                float val = fmaxf(acc[t][4 * q + e] + sh1[co + e], 0.f);
                ushort_t h, m2, l;
                split3(val, h, m2, l);
                ((ushort_t*)&h4)[e] = h; ((ushort_t*)&m4)[e] = m2; ((ushort_t*)&l4)[e] = l;
            }
            int so = (((c8o * 3) * H2PIX + pb[t]) << 3) + (co & 7);
            *(ushort4*)&lsh[so] = h4;
            *(ushort4*)&lsh[so + H2PIX * 8] = m4;
            *(ushort4*)&lsh[so + 2 * H2PIX * 8] = l4;
        }
    }
    __syncthreads();

    CONV(wf2);
    float* ob = out + (long)img * H2PIX * CIN;
    #pragma unroll
    for (int t = 0; t < TPW; ++t) {
        #pragma unroll
        for (int q = 0; q < 4; ++q) {
            int co = ntb0 * 32 + q * 8 + 4 * hi;
            float4 r = *(const float4*)(ib + (long)pb[t] * CIN + co);
            float v0 = acc[t][4 * q + 0] + sh2[co + 0] + r.x;
            float v1 = acc[t][4 * q + 1] + sh2[co + 1] + r.y;
            float v2 = acc[t][4 * q + 2] + sh2[co + 2] + r.z;
            float v3 = acc[t][4 * q + 3] + sh2[co + 3] + r.w;
            *(float4*)(ob + (long)pb[t] * CIN + co) =
                make_float4(fmaxf(v0, 0.f), fmaxf(v1, 0.f), fmaxf(v2, 0.f), fmaxf(v3, 0.f));
        }
    }
}

// --- avgpool (8x8, padded fp32 10x10x64) + FC (64->10) ----------------------
__global__ void pool_fc(const float* __restrict__ X, const float* __restrict__ fw,
                        const float* __restrict__ fb, float* __restrict__ out) {
    int b = blockIdx.x;
    int c = threadIdx.x;
    float s = 0.f;
    #pragma unroll
    for (int p = 0; p < 64; ++p) {
        int y = p >> 3, x = p & 7;
        s += X[(((long)b * 10 + y + 1) * 10 + (x + 1)) * 64 + c];
    }
    __shared__ float pooled[64];
    pooled[c] = s * (1.f / 64.f);
    __syncthreads();
    if (c < 10) {
        float acc = fb[c];
        #pragma unroll
        for (int k = 0; k < 64; ++k) acc += pooled[k] * fw[c * 64 + k];
        out[b * 10 + c] = acc;
    }
}

extern "C" void kernel_launch(void* const* d_in, const int* in_sizes, int n_in,
                              void* d_out, int out_size, void* d_ws, size_t ws_size,
                              hipStream_t stream) {
    const float* x       = (const float*)d_in[0];
    const float* conv1_w = (const float*)d_in[1];
    const float* conv1_b = (const float*)d_in[2];
    const float* bn_g    = (const float*)d_in[3];
    const float* bn_b    = (const float*)d_in[4];
    const float* bn_m    = (const float*)d_in[5];
    const float* bn_v    = (const float*)d_in[6];
    const float* hn_w2   = (const float*)d_in[7];
    const float* hn_b2   = (const float*)d_in[8];
    const float* hn_w1   = (const float*)d_in[9];
    const float* hn_b1   = (const float*)d_in[10];
    const float* z_all   = (const float*)d_in[11];
    const float* res_w6  = (const float*)d_in[12];
    const float* res_b6  = (const float*)d_in[13];
    const float* res_w12 = (const float*)d_in[14];
    const float* res_b12 = (const float*)d_in[15];
    const float* fin_w   = (const float*)d_in[16];
    const float* fin_b   = (const float*)d_in[17];
    float* outp = (float*)d_out;

    float* wsf      = (float*)d_ws;
    float* Wg       = wsf;                       // 557568 fp32
    float* bnsc     = wsf + 557568;
    float* bnsh     = wsf + 559936;
    float* shp13    = wsf + 562304;              // 32
    float* shp25    = wsf + 564864;              // 64
    ushort_t* Wfrag = (ushort_t*)(wsf + 565248); // 1866240 shorts

    float* A0f = (float*)((char*)d_ws + (size_t)(16) * (1 << 20));
    float* A1f = (float*)((char*)d_ws + (size_t)(80) * (1 << 20));
    float* A2f = (float*)((char*)d_ws + (size_t)(144) * (1 << 20));

    static const int wfoff[36] = WFOFF_LIST;

    prep<<<20, 256, 0, stream>>>(bn_g, bn_b, bn_m, bn_v, res_b6, res_b12,
                                 bnsc, bnsh, shp13, shp25);
    hyper_kernel<<<242, 256, 0, stream>>>(z_all, hn_w2, hn_b2, hn_w1, hn_b1, bnsc, Wg);
    split_w<<<dim3(168, 36), 256, 0, stream>>>(Wg, res_w6, res_w12, Wfrag);
    conv_first<<<4096, 256, 0, stream>>>(x, conv1_w, conv1_b, bn_g, bn_b, bn_m, bn_v, A0f);

    // ---- stage 1: unfused conv_s1 pairs (unpadded 32x32x16) ----
    float* X = A0f; float* T1 = A1f; float* T2 = A2f;
    for (int i = 0; i < 6; ++i) {
        int L1 = 2 * i, L2 = 2 * i + 1;
        conv_s1<0><<<4096, 256, 0, stream>>>(
            X, Wfrag + wfoff[L1], bnsh + (L1 + 1) * 64, nullptr, T1);
        conv_s1<1><<<4096, 256, 0, stream>>>(
            T1, Wfrag + wfoff[L2], bnsh + (L2 + 1) * 64, X, T2);
        float* tmp = X; X = T2; T2 = tmp;
    }
    // X = A0f.
    // ---- i = 6 transition ----
    pad_zero_f32<<<2176, 256, 0, stream>>>(A1f, 18, 8);
    conv_mfma<16,32,32,2,8,16,1><<<2048, 256, 0, stream>>>(
        A0f, Wfrag + wfoff[12], bnsh + 13 * 64, A1f);              // -> padded 18x18x32
    pad_zero_f32<<<2176, 256, 0, stream>>>(A2f, 18, 8);
    conv_s23<32,32,16,1,128,3,1,3><<<2048, 256, 0, stream>>>(
        A1f, Wfrag + wfoff[13], shp13, A0f, A2f);                  // + 1x1s2 res (k-step)

    // ---- stage 2: whole-image fused pairs, 512 threads (A2f <-> A1f) ----
    X = A2f; float* T = A1f;
    for (int i = 7; i < 12; ++i) {
        int L1 = 2 * i, L2 = 2 * i + 1;
        block_fused<32,16,1,512><<<1024, 512, 0, stream>>>(
            X, Wfrag + wfoff[L1], Wfrag + wfoff[L2],
            bnsh + (L1 + 1) * 64, bnsh + (L2 + 1) * 64, T);
        float* tmp = X; X = T; T = tmp;
    }
    // X = A1f (padded 18x18x32).
    // ---- i = 12 transition ----
    pad_zero_f32<<<2304, 256, 0, stream>>>(A0f, 10, 16);
    conv_s23<32,64,16,2,64,0,0,5><<<1024, 256, 0, stream>>>(
        A1f, Wfrag + wfoff[24], bnsh + 25 * 64, nullptr, A0f);     // -> padded 10x10x64
    pad_zero_f32<<<2304, 256, 0, stream>>>(A2f, 10, 16);
    conv_s23<64,64,8,1,64,2,2,6><<<1024, 256, 0, stream>>>(
        A0f, Wfrag + wfoff[25], shp25, A1f, A2f);                  // + 1x1s2 res (k-steps)

    // ---- stage 3: whole-image fused pairs, 256 threads (A2f <-> A0f) ----
    X = A2f; T = A0f;
    for (int i = 13; i < 18; ++i) {
        int L1 = 2 * i, L2 = 2 * i + 1;
        block_fused<64,8,1,256><<<1024, 256, 0, stream>>>(
            X, Wfrag + wfoff[L1], Wfrag + wfoff[L2],
            bnsh + (L1 + 1) * 64, bnsh + (L2 + 1) * 64, T);
        float* tmp = X; X = T; T = tmp;
    }
    // X = A0f.
    pool_fc<<<1024, 64, 0, stream>>>(A0f, fin_w, fin_b, outp);
}

// Round 14
// 1273.284 us; speedup vs baseline: 1.0828x; 1.0828x over previous
//
#include <hip/hip_runtime.h>
#include <hip/hip_bf16.h>

// ---------------------------------------------------------------------------
// Hypernetwork ResNet, bf16x3-split MFMA (fp32-equivalent precision).
// R14 = R10 best-known config + XCD-aware block swizzle (bijective, all
// grids %8==0) + s_setprio(1) around MFMA K-loops (helps co-resident
// blocks at different phases). Stage 1: unfused conv_s1. Stage 2: whole-
// image single-buffer block_fused 256t/TPW=2. Stage 3: block_fused 256t/
// TPW=1 (at MFMA floor). Transitions via conv_mfma / conv_s23.
// ---------------------------------------------------------------------------

typedef __attribute__((ext_vector_type(8))) short bf16x8;
typedef __attribute__((ext_vector_type(4))) float f32x4;
typedef __attribute__((ext_vector_type(16))) float f32x16;
typedef unsigned short ushort_t;

#define OFFS_LIST {0,1,2,3,4,5,6,7,8,9,10,11,12,14,18,22,26,30,34,38,42,46,50,54,58,66,82,98,114,130,146,162,178,194,210,226,242}
#define K_LIST    {1,1,1,1,1,1,1,1,1,1,1,1,1,2,2,2,2,2,2,2,2,2,2,2,2,4,4,4,4,4,4,4,4,4,4,4}
#define H_LIST    {1,1,1,1,1,1,1,1,1,1,1,1,2,2,2,2,2,2,2,2,2,2,2,2,4,4,4,4,4,4,4,4,4,4,4,4}
#define WOFF_LIST {0,2304,4608,6912,9216,11520,13824,16128,18432,20736,23040,25344,27648,32256,41472,50688,59904,69120,78336,87552,96768,105984,115200,124416,133632,152064,188928,225792,262656,299520,336384,373248,410112,446976,483840,520704}
#define CIN_LIST  {16,16,16,16,16,16,16,16,16,16,16,16,16,32,32,32,32,32,32,32,32,32,32,32,32,64,64,64,64,64,64,64,64,64,64,64}
#define COUT_LIST {16,16,16,16,16,16,16,16,16,16,16,16,32,32,32,32,32,32,32,32,32,32,32,32,64,64,64,64,64,64,64,64,64,64,64,64}
#define WFOFF_LIST {0,7680,15360,23040,30720,38400,46080,53760,61440,69120,76800,84480,92160,107520,139776,170496,201216,231936,262656,293376,324096,354816,385536,416256,446976,508416,637440,760320,883200,1006080,1128960,1251840,1374720,1497600,1620480,1743360}

__constant__ int d_offs[37]  = OFFS_LIST;
__constant__ int d_k[36]     = K_LIST;
__constant__ int d_hh[36]    = H_LIST;
__constant__ int d_woff[36]  = WOFF_LIST;
__constant__ int d_cin[36]   = CIN_LIST;
__constant__ int d_cout[36]  = COUT_LIST;
__constant__ int d_wfoff[36] = WFOFF_LIST;

__device__ inline void split3(float x, ushort_t& h, ushort_t& m, ushort_t& l) {
    unsigned xb = __float_as_uint(x);
    unsigned hb = (xb + 0x8000u) >> 16;
    float fh = __uint_as_float(hb << 16);
    float r = x - fh;
    unsigned mb = (__float_as_uint(r) + 0x8000u) >> 16;
    float fm = __uint_as_float(mb << 16);
    float r2 = r - fm;
    unsigned lb = (__float_as_uint(r2) + 0x8000u) >> 16;
    h = (ushort_t)hb; m = (ushort_t)mb; l = (ushort_t)lb;
}
__device__ inline float b2f(ushort_t u) { return __uint_as_float(((unsigned)u) << 16); }

// XCD-aware bijective block swizzle (requires gridDim.x % 8 == 0).
__device__ inline int swz_bid() {
    int nb = gridDim.x;
    int q = nb >> 3;
    return (blockIdx.x & 7) * q + (blockIdx.x >> 3);
}

// --- prep: BN scale/shift; shp13 = bnsh[14]+rb6; shp25 = bnsh[26]+rb12 ------
__global__ void prep(const float* __restrict__ g, const float* __restrict__ be,
                     const float* __restrict__ m, const float* __restrict__ v,
                     const float* __restrict__ rb6, const float* __restrict__ rb12,
                     float* __restrict__ sc, float* __restrict__ sh,
                     float* __restrict__ shp13, float* __restrict__ shp25) {
    int i = blockIdx.x * blockDim.x + threadIdx.x;
    if (i < 2368) {
        float s = g[i] * rsqrtf(v[i] + 1e-5f);
        sc[i] = s;
        sh[i] = be[i] - m[i] * s;
    } else if (i < 2368 + 32) {
        int c = i - 2368;
        int idx2 = 14 * 64 + c;
        float s = g[idx2] * rsqrtf(v[idx2] + 1e-5f);
        shp13[c] = be[idx2] - m[idx2] * s + rb6[c];
    } else if (i < 2400 + 64) {
        int c = i - 2400;
        int idx2 = 26 * 64 + c;
        float s = g[idx2] * rsqrtf(v[idx2] + 1e-5f);
        shp25[c] = be[idx2] - m[idx2] * s + rb12[c];
    }
}

// --- Hypernetwork: one block per z-row. Emits fp32 weights [tap][ci][co]. ---
__global__ void hyper_kernel(const float* __restrict__ z_all, const float* __restrict__ w2,
                             const float* __restrict__ b2, const float* __restrict__ w1,
                             const float* __restrict__ b1, const float* __restrict__ bnsc,
                             float* __restrict__ Wg) {
    int n = blockIdx.x;
    int tid = threadIdx.x;
    __shared__ float zrow[64];
    __shared__ float hin[1024];
    if (tid < 64) zrow[tid] = z_all[n * 64 + tid];
    __syncthreads();
    for (int mcol = tid; mcol < 1024; mcol += 256) {
        float acc = b2[mcol];
        #pragma unroll 8
        for (int d = 0; d < 64; ++d) acc += zrow[d] * w2[d * 1024 + mcol];
        hin[mcol] = acc;
    }
    __syncthreads();
    int L = 0;
    while (n >= d_offs[L + 1]) ++L;
    int r = n - d_offs[L];
    int kk = d_k[L];
    int a = r / kk, bb = r % kk;
    int Cin = kk * 16;
    int Cout = d_hh[L] * 16;
    const float* scp = bnsc + (L + 1) * 64;
    float* wp = Wg + d_woff[L];
    for (int e = tid; e < 2304; e += 256) {
        int i = e / 144, o = e % 144;
        int j = o / 9, tap = o % 9;
        float acc = b1[o];
        #pragma unroll 8
        for (int d = 0; d < 64; ++d) acc += hin[i * 64 + d] * w1[d * 144 + o];
        int co = a * 16 + i;
        acc *= scp[co];
        wp[(tap * Cin + (bb * 16 + j)) * Cout + co] = acc;
    }
}

// --- split weights into bf16x3 fragment blocks ------------------------------
__global__ void split_w(const float* __restrict__ Wg, const float* __restrict__ rw6,
                        const float* __restrict__ rw12, ushort_t* __restrict__ Wf) {
    int L = blockIdx.y;
    int CIN = d_cin[L], COUT = d_cout[L];
    int idx = blockIdx.x * 256 + threadIdx.x;
    int j = idx & 7, lane = (idx >> 3) & 63, t = idx >> 9;
    int hi = lane >> 5;
    float wv;
    int base;
    if (L < 13) {                       // 16x16x32 fragment format
        int K = 9 * CIN, NKS = (K + 31) / 32, NT = COUT / 16;
        if (t >= NKS * NT) return;
        int nt = t % NT, ks = t / NT;
        int k = ks * 32 + (lane >> 4) * 8 + j;
        int co = nt * 16 + (lane & 15);
        wv = (k < K) ? Wg[d_woff[L] + k * COUT + co] : 0.f;
        base = d_wfoff[L] + ((ks * NT + nt) * 3) * 512 + lane * 8 + j;
    } else {                            // 32x32x16, padded taps (10), tap-inner
        int CG8 = CIN / 8, NKS = 5 * CG8, NT = COUT / 32;
        int TKS = NKS + ((L == 25) ? 2 : ((L == 13) ? 1 : 0));
        if (t >= TKS * NT) return;
        int nt = t % NT, ks = t / NT;
        int co = nt * 32 + (lane & 31);
        if (ks < NKS) {
            int o = 2 * ks + hi, tap = o % 10, c8 = o / 10;
            int ci = c8 * 8 + j;
            wv = (tap < 9) ? Wg[d_woff[L] + (tap * CIN + ci) * COUT + co] : 0.f;
        } else if (L == 25) {           // appended 1x1-s2 residual (32->64)
            int k = (ks - NKS) * 16 + hi * 8 + j;
            wv = rw12[co * 32 + k];
        } else {                        // L13 appended 1x1-s2 residual (16->32)
            int k = hi * 8 + j;
            wv = rw6[co * 16 + k];
        }
        base = d_wfoff[L] + ((ks * NT + nt) * 3) * 512 + lane * 8 + j;
    }
    ushort_t h, m, l;
    split3(wv, h, m, l);
    Wf[base] = h; Wf[base + 512] = m; Wf[base + 1024] = l;
}

// --- First conv: 3->16, NCHW in -> NHWC fp32 out ----------------------------
__global__ void conv_first(const float* __restrict__ x, const float* __restrict__ cw,
                           const float* __restrict__ cb, const float* __restrict__ g,
                           const float* __restrict__ be, const float* __restrict__ m,
                           const float* __restrict__ v, float* __restrict__ out) {
    int idx = swz_bid() * 256 + threadIdx.x;
    int px = idx & 31; int t = idx >> 5;
    int py = t & 31;   int b = t >> 5;
    float acc[16];
    #pragma unroll
    for (int co = 0; co < 16; ++co) acc[co] = 0.f;
    const float* ip = x + (long)b * 3 * 1024;
    #pragma unroll 1
    for (int ci = 0; ci < 3; ++ci) {
        #pragma unroll 1
        for (int ky = 0; ky < 3; ++ky) {
            int iy = py + ky - 1;
            if ((unsigned)iy >= 32u) continue;
            #pragma unroll
            for (int kx = 0; kx < 3; ++kx) {
                int ix = px + kx - 1;
                if ((unsigned)ix < 32u) {
                    float xv = ip[ci * 1024 + iy * 32 + ix];
                    #pragma unroll
                    for (int co = 0; co < 16; ++co)
                        acc[co] += xv * cw[co * 27 + ci * 9 + ky * 3 + kx];
                }
            }
        }
    }
    long o = ((long)(b * 32 + py) * 32 + px) * 16;
    #pragma unroll
    for (int co = 0; co < 16; ++co) {
        float s = g[co] * rsqrtf(v[co] + 1e-5f);
        float val = (acc[co] + cb[co] - m[co]) * s + be[co];
        out[o + co] = fmaxf(val, 0.f);
    }
}

// --- zero the halo ring of a padded fp32 NHWC buffer ------------------------
__global__ void pad_zero_f32(float* __restrict__ buf, int H2, int C4) {
    int idx = blockIdx.x * 256 + threadIdx.x;
    int nb = 2 * H2 + 2 * (H2 - 2);
    int total = 1024 * nb * C4;
    if (idx >= total) return;
    int ch = idx % C4; int t = idx / C4;
    int bp = t % nb; int img = t / nb;
    int y, x;
    if (bp < H2) { y = 0; x = bp; }
    else if (bp < 2 * H2) { y = H2 - 1; x = bp - H2; }
    else { int s = bp - 2 * H2; y = 1 + (s >> 1); x = (s & 1) ? H2 - 1 : 0; }
    long off = (((long)img * H2 + y) * H2 + x) * (C4 * 4) + ch * 4;
    *(float4*)(buf + off) = make_float4(0.f, 0.f, 0.f, 0.f);
}

// --- Stage-1 conv_s1 (unfused): CIN=COUT=16, H=32, unpadded fp32 NHWC -------
template<int MODE>
__global__ __launch_bounds__(256) void conv_s1(
        const float* __restrict__ in, const ushort_t* __restrict__ wf,
        const float* __restrict__ shp, const float* __restrict__ res,
        float* __restrict__ out) {
    constexpr int W2 = 34, SLABPIX = 10 * W2;
    constexpr int NKS = 5;

    __shared__ uint4 lds[6 * SLABPIX];

    int tid = threadIdx.x, lane = tid & 63, wid = tid >> 6;
    int g = lane >> 4, r16 = lane & 15;
    int bid = swz_bid();
    int img = bid >> 2, blocky = bid & 3;
    int row0 = blocky * 8;

    const ushort_t* wfl = wf + lane * 8;
    bf16x8 wv[NKS][3];
    #pragma unroll
    for (int ks = 0; ks < NKS; ++ks)
        #pragma unroll
        for (int p = 0; p < 3; ++p)
            wv[ks][p] = *(const bf16x8*)(wfl + (ks * 3 + p) * 512);
    #pragma unroll
    for (int ks = 0; ks < NKS; ++ks)
        #pragma unroll
        for (int p = 0; p < 3; ++p)
            asm volatile("" : "+v"(wv[ks][p]));

    const float* ib = in + (long)img * (32 * 32 * 16);
    for (int it = tid; it < SLABPIX * 2; it += 256) {
        int pix = it % SLABPIX, cc = it / SLABPIX;
        int sr = pix / W2, sc = pix % W2;
        int gy = row0 - 1 + sr, gx = sc - 1;
        float vv[8];
        if ((unsigned)gy < 32u && (unsigned)gx < 32u) {
            const float4* p4 = (const float4*)(ib + ((long)gy * 32 + gx) * 16 + cc * 8);
            float4 a0 = p4[0], a1 = p4[1];
            vv[0]=a0.x; vv[1]=a0.y; vv[2]=a0.z; vv[3]=a0.w;
            vv[4]=a1.x; vv[5]=a1.y; vv[6]=a1.z; vv[7]=a1.w;
        } else {
            #pragma unroll
            for (int q = 0; q < 8; ++q) vv[q] = 0.f;
        }
        union { ushort_t u[8]; uint4 q; } H, M, L;
        #pragma unroll
        for (int q = 0; q < 8; ++q) split3(vv[q], H.u[q], M.u[q], L.u[q]);
        lds[(cc * 3 + 0) * SLABPIX + pix] = H.q;
        lds[(cc * 3 + 1) * SLABPIX + pix] = M.q;
        lds[(cc * 3 + 2) * SLABPIX + pix] = L.q;
    }
    __syncthreads();

    int pbase[4];
    #pragma unroll
    for (int mt = 0; mt < 4; ++mt) {
        int pid = (wid * 4 + mt) * 16 + r16;
        pbase[mt] = (pid >> 5) * W2 + (pid & 31);
    }

    f32x4 acc[4] = {};

    __builtin_amdgcn_s_setprio(1);
    #pragma unroll
    for (int ks = 0; ks < NKS; ++ks) {
        int k0 = ks * 32 + g * 8;
        int tap = k0 >> 4;
        int ci8 = (k0 >> 3) & 1;
        int ky = (tap * 11) >> 5;
        int kx = tap - 3 * ky;
        bool dead = (ks == NKS - 1) && (g >= 2);
        int ofs = dead ? 0 : (ci8 * 3) * SLABPIX + ky * W2 + kx;
        #pragma unroll
        for (int mt = 0; mt < 4; ++mt) {
            int e16 = dead ? 0 : ofs + pbase[mt];
            bf16x8 ah = *(const bf16x8*)&lds[e16];
            bf16x8 am = *(const bf16x8*)&lds[e16 + SLABPIX];
            bf16x8 al = *(const bf16x8*)&lds[e16 + 2 * SLABPIX];
            f32x4 c = acc[mt];
            c = __builtin_amdgcn_mfma_f32_16x16x32_bf16(ah, wv[ks][0], c, 0, 0, 0);
            c = __builtin_amdgcn_mfma_f32_16x16x32_bf16(ah, wv[ks][1], c, 0, 0, 0);
            c = __builtin_amdgcn_mfma_f32_16x16x32_bf16(am, wv[ks][0], c, 0, 0, 0);
            c = __builtin_amdgcn_mfma_f32_16x16x32_bf16(ah, wv[ks][2], c, 0, 0, 0);
            c = __builtin_amdgcn_mfma_f32_16x16x32_bf16(am, wv[ks][1], c, 0, 0, 0);
            c = __builtin_amdgcn_mfma_f32_16x16x32_bf16(al, wv[ks][0], c, 0, 0, 0);
            acc[mt] = c;
        }
    }
    __builtin_amdgcn_s_setprio(0);

    #pragma unroll
    for (int mt = 0; mt < 4; ++mt) {
        #pragma unroll
        for (int reg = 0; reg < 4; ++reg) {
            int pid = (wid * 4 + mt) * 16 + g * 4 + reg;
            int gy = row0 + (pid >> 5), gx = pid & 31;
            long oidx = (((long)img * 32 + gy) * 32 + gx) * 16 + r16;
            float val = acc[mt][reg] + shp[r16];
            if (MODE == 1) val += res[oidx];
            out[oidx] = fmaxf(val, 0.f);
        }
    }
}

// --- conv_mfma (i=6 conv1 only): 16x16x32 MFMA, LDS bf16x3 ------------------
template<int CIN, int COUT, int HIN, int STRIDE, int TH, int TW, int OUTF>
__global__ __launch_bounds__(256) void conv_mfma(
        const float* __restrict__ in, const ushort_t* __restrict__ wf,
        const float* __restrict__ shp, float* __restrict__ out) {
    constexpr int HOUT = HIN / STRIDE;
    constexpr int H2O = HOUT + 2;
    constexpr int CG8 = CIN / 8;
    constexpr int IH = (TH - 1) * STRIDE + 3;
    constexpr int IW = (TW - 1) * STRIDE + 3;
    constexpr int K = 9 * CIN;
    constexpr int NKS = (K + 31) / 32;
    constexpr bool TAIL = (K % 32) != 0;
    constexpr int NT = COUT / 16;
    constexpr int MTW = TH * TW / 64;
    constexpr int PADC = ((2 - (IH * IW)) % 8 + 8) % 8;
    constexpr int CSTU = IH * IW + PADC;
    constexpr int PST = CG8 * CSTU;
    constexpr int TX = HOUT / TW, TY = HOUT / TH;

    __shared__ uint4 lds[3 * PST];

    int tid = threadIdx.x;
    int bid = swz_bid();
    int tile = bid % (TY * TX);
    int b = bid / (TY * TX);
    int ty = tile / TX, tx = tile % TX;
    int Y0 = ty * TH, X0 = tx * TW;
    int gy0 = Y0 * STRIDE - 1, gx0 = X0 * STRIDE - 1;

    for (int e = tid; e < CG8 * IH * IW; e += 256) {
        int c8 = e / (IH * IW); int rr = e % (IH * IW);
        int ly = rr / IW, lx = rr % IW;
        int gy = gy0 + ly, gx = gx0 + lx;
        float vv[8];
        if ((unsigned)gy < (unsigned)HIN && (unsigned)gx < (unsigned)HIN) {
            const float4* p = (const float4*)(in + ((long)(b * HIN + gy) * HIN + gx) * CIN + c8 * 8);
            float4 a0 = p[0], a1 = p[1];
            vv[0]=a0.x; vv[1]=a0.y; vv[2]=a0.z; vv[3]=a0.w;
            vv[4]=a1.x; vv[5]=a1.y; vv[6]=a1.z; vv[7]=a1.w;
        } else {
            #pragma unroll
            for (int q = 0; q < 8; ++q) vv[q] = 0.f;
        }
        union { ushort_t u[8]; uint4 q4; } H, M, L;
        #pragma unroll
        for (int q = 0; q < 8; ++q) split3(vv[q], H.u[q], M.u[q], L.u[q]);
        int a16 = c8 * CSTU + rr;
        lds[a16] = H.q4; lds[PST + a16] = M.q4; lds[2 * PST + a16] = L.q4;
    }
    __syncthreads();

    int lane = tid & 63, wid = tid >> 6;
    int g = lane >> 4, r16 = lane & 15;

    f32x4 acc[MTW][NT] = {};

    int pbase[MTW];
    #pragma unroll
    for (int mt = 0; mt < MTW; ++mt) {
        int pid = (wid + 4 * mt) * 16 + r16;
        int py = pid / TW, px = pid % TW;
        pbase[mt] = (py * STRIDE) * IW + px * STRIDE;
    }

    __builtin_amdgcn_s_setprio(1);
    #pragma unroll
    for (int ks = 0; ks < NKS; ++ks) {
        bf16x8 bfr[NT][3];
        #pragma unroll
        for (int nt = 0; nt < NT; ++nt)
            #pragma unroll
            for (int p = 0; p < 3; ++p)
                bfr[nt][p] = *(const bf16x8*)(wf + ((ks * NT + nt) * 3 + p) * 512 + lane * 8);

        int k0 = ks * 32 + g * 8;
        int tap = k0 / CIN;
        int ci8 = (k0 % CIN) >> 3;
        int ky = (tap * 11) >> 5;
        int kx = tap - 3 * ky;
        int ofs = ci8 * CSTU + ky * IW + kx;

        #pragma unroll
        for (int mt = 0; mt < MTW; ++mt) {
            int e16 = ofs + pbase[mt];
            if (TAIL && ks == NKS - 1) e16 = (g < 2) ? e16 : 0;
            const uint4* ap = lds + e16;
            bf16x8 ah = *(const bf16x8*)(ap);
            bf16x8 am = *(const bf16x8*)(ap + PST);
            bf16x8 al = *(const bf16x8*)(ap + 2 * PST);
            #pragma unroll
            for (int nt = 0; nt < NT; ++nt) {
                f32x4 c = acc[mt][nt];
                c = __builtin_amdgcn_mfma_f32_16x16x32_bf16(ah, bfr[nt][0], c, 0, 0, 0);
                c = __builtin_amdgcn_mfma_f32_16x16x32_bf16(ah, bfr[nt][1], c, 0, 0, 0);
                c = __builtin_amdgcn_mfma_f32_16x16x32_bf16(am, bfr[nt][0], c, 0, 0, 0);
                c = __builtin_amdgcn_mfma_f32_16x16x32_bf16(ah, bfr[nt][2], c, 0, 0, 0);
                c = __builtin_amdgcn_mfma_f32_16x16x32_bf16(am, bfr[nt][1], c, 0, 0, 0);
                c = __builtin_amdgcn_mfma_f32_16x16x32_bf16(al, bfr[nt][0], c, 0, 0, 0);
                acc[mt][nt] = c;
            }
        }
    }
    __builtin_amdgcn_s_setprio(0);

    #pragma unroll
    for (int mt = 0; mt < MTW; ++mt) {
        #pragma unroll
        for (int nt = 0; nt < NT; ++nt) {
            int co = nt * 16 + r16;
            float shv = shp[co];
            #pragma unroll
            for (int reg = 0; reg < 4; ++reg) {
                int pid = (wid + 4 * mt) * 16 + g * 4 + reg;
                int py = pid / TW, px = pid % TW;
                int gy = Y0 + py, gx = X0 + px;
                float val = fmaxf(acc[mt][nt][reg] + shv, 0.f);
                if (OUTF == 0) {
                    out[((long)(b * HOUT + gy) * HOUT + gx) * COUT + co] = val;
                } else {
                    out[(((long)b * H2O + gy + 1) * H2O + gx + 1) * COUT + co] = val;
                }
            }
        }
    }
}

// --- conv_s23: LDS-slab conv, 32x32x16 MFMA, padded fp32 NHWC io ------------
template<int CIN, int COUT, int HIN, int STRIDE, int PXB, int MODE, int RKS, int CHUNK>
__global__ __launch_bounds__(256) void conv_s23(
        const float* __restrict__ in, const ushort_t* __restrict__ wf,
        const float* __restrict__ shp, const float* __restrict__ res,
        float* __restrict__ out) {
    constexpr int HOUT = HIN / STRIDE;
    constexpr int H2I = HIN + 2, H2O = HOUT + 2;
    constexpr int C8 = CIN / 8;
    constexpr int NKS = 5 * C8;
    constexpr int TKS = NKS + RKS;
    constexpr int NC = TKS / CHUNK;
    constexpr int NTT = COUT / 32;
    constexpr int ROWSB = PXB / HOUT;
    constexpr int SLABR = (ROWSB - 1) * STRIDE + 3;
    constexpr int SLABPIX = SLABR * H2I;
    constexpr int NBLK = HOUT / ROWSB;
    constexpr int RESU = 3 * C8 * SLABPIX;
    constexpr int LDSU = RESU + ((MODE == 2 || MODE == 3) ? 768 : 0);

    __shared__ uint4 lds[LDSU];

    int tid = threadIdx.x, lane = tid & 63, wid = tid >> 6;
    int lp = lane & 31, hi = lane >> 5;
    int bid = swz_bid();
    int img = bid / NBLK, blocky = bid % NBLK;
    int pxg = wid / NTT, ntb = wid % NTT;
    int pix0 = pxg * 32 + lp;
    int py_blk = pix0 / HOUT, px = pix0 % HOUT;
    int py = blocky * ROWSB + py_blk;
    int slabrow0 = blocky * ROWSB * STRIDE;

    const ushort_t* wfl = wf + lane * 8;

    bf16x8 wA[CHUNK][3], wB[CHUNK][3];
    auto LW = [&](int c, bf16x8 (&w)[CHUNK][3]) {
        #pragma unroll
        for (int i = 0; i < CHUNK; ++i) {
            int ks = c * CHUNK + i;
            #pragma unroll
            for (int pp = 0; pp < 3; ++pp)
                w[i][pp] = *(const bf16x8*)(wfl + ((ks * NTT + ntb) * 3 + pp) * 512);
        }
    };

    LW(0, wA);
    if (NC > 1) LW(1, wB);

    const float* ib = in + (long)img * H2I * H2I * CIN;
    for (int it = tid; it < SLABPIX * C8; it += 256) {
        int pix = it % SLABPIX, cc = it / SLABPIX;
        int sr = pix / H2I, sc = pix % H2I;
        const float* p4 = ib + ((long)(slabrow0 + sr) * H2I + sc) * CIN + cc * 8;
        float4 a0 = ((const float4*)p4)[0], a1 = ((const float4*)p4)[1];
        float vv[8] = {a0.x, a0.y, a0.z, a0.w, a1.x, a1.y, a1.z, a1.w};
        union { ushort_t u[8]; uint4 q; } H, M, L;
        #pragma unroll
        for (int q = 0; q < 8; ++q) split3(vv[q], H.u[q], M.u[q], L.u[q]);
        int u0 = cc * 3;
        lds[u0 * SLABPIX + pix] = H.q;
        lds[(u0 + 1) * SLABPIX + pix] = M.q;
        lds[(u0 + 2) * SLABPIX + pix] = L.q;
    }
    if (MODE == 2) {
        for (int it = tid; it < 256; it += 256) {
            int pix = it & 63, cc = it >> 6;
            int ry = pix >> 3, rx = pix & 7;
            const float* r4 = res + (((long)img * 18 + (2 * ry + 1)) * 18 + (2 * rx + 1)) * 32 + cc * 8;
            float4 a0 = ((const float4*)r4)[0], a1 = ((const float4*)r4)[1];
            float vv[8] = {a0.x, a0.y, a0.z, a0.w, a1.x, a1.y, a1.z, a1.w};
            union { ushort_t u[8]; uint4 q; } H, M, L;
            #pragma unroll
            for (int q = 0; q < 8; ++q) split3(vv[q], H.u[q], M.u[q], L.u[q]);
            int u0 = RESU + cc * 3 * 64;
            lds[u0 + pix] = H.q;
            lds[u0 + 64 + pix] = M.q;
            lds[u0 + 128 + pix] = L.q;
        }
    }
    if (MODE == 3) {
        for (int it = tid; it < 256; it += 256) {
            int opix = it >> 1, cg = it & 1;
            int r = opix / 16, cxx = opix % 16;
            int gy = (blocky * 8 + r) * 2, gx = cxx * 2;
            const float* r4 = res + (((long)img * 32 + gy) * 32 + gx) * 16 + cg * 8;
            float4 a0 = ((const float4*)r4)[0], a1 = ((const float4*)r4)[1];
            float vv[8] = {a0.x, a0.y, a0.z, a0.w, a1.x, a1.y, a1.z, a1.w};
            union { ushort_t u[8]; uint4 q; } H, M, L;
            #pragma unroll
            for (int q = 0; q < 8; ++q) split3(vv[q], H.u[q], M.u[q], L.u[q]);
            int u0 = RESU + opix * 6;
            lds[u0 + cg] = H.q;
            lds[u0 + 2 + cg] = M.q;
            lds[u0 + 4 + cg] = L.q;
        }
    }
    __syncthreads();

    int pbase = (py_blk * STRIDE) * H2I + px * STRIDE;
    f32x16 acc = {};

    auto DOC = [&](int c, bf16x8 (&w)[CHUNK][3]) {
        #pragma unroll
        for (int i = 0; i < CHUNK; ++i) {
            int ks = c * CHUNK + i;
            bf16x8 x0, x1, x2;
            if (RKS > 0 && ks >= NKS) {
                if (MODE == 2) {
                    int o2 = 2 * (ks - NKS) + hi;
                    int a = RESU + o2 * 3 * 64 + pix0;
                    x0 = *(const bf16x8*)&lds[a];
                    x1 = *(const bf16x8*)&lds[a + 64];
                    x2 = *(const bf16x8*)&lds[a + 128];
                } else {
                    int a = RESU + pix0 * 6 + hi;
                    x0 = *(const bf16x8*)&lds[a];
                    x1 = *(const bf16x8*)&lds[a + 2];
                    x2 = *(const bf16x8*)&lds[a + 4];
                }
            } else {
                int o = 2 * ks + hi;
                int tap = o % 10, c8i = o / 10;
                int ky = (tap * 11) >> 5, kx = tap - 3 * ky;
                int t16 = (tap == 9) ? 0 : (ky * H2I + kx);
                int a = (c8i * 3) * SLABPIX + pbase + t16;
                x0 = *(const bf16x8*)&lds[a];
                x1 = *(const bf16x8*)&lds[a + SLABPIX];
                x2 = *(const bf16x8*)&lds[a + 2 * SLABPIX];
            }
            acc = __builtin_amdgcn_mfma_f32_32x32x16_bf16(w[i][0], x0, acc, 0, 0, 0);
            acc = __builtin_amdgcn_mfma_f32_32x32x16_bf16(w[i][1], x0, acc, 0, 0, 0);
            acc = __builtin_amdgcn_mfma_f32_32x32x16_bf16(w[i][0], x1, acc, 0, 0, 0);
            acc = __builtin_amdgcn_mfma_f32_32x32x16_bf16(w[i][2], x0, acc, 0, 0, 0);
            acc = __builtin_amdgcn_mfma_f32_32x32x16_bf16(w[i][1], x1, acc, 0, 0, 0);
            acc = __builtin_amdgcn_mfma_f32_32x32x16_bf16(w[i][0], x2, acc, 0, 0, 0);
        }
    };

    __builtin_amdgcn_s_setprio(1);
    #pragma unroll 1
    for (int c = 0; c < NC; c += 2) {
        DOC(c, wA);
        if (c + 2 < NC) LW(c + 2, wA);
        if (c + 1 < NC) { DOC(c + 1, wB); if (c + 3 < NC) LW(c + 3, wB); }
    }
    __builtin_amdgcn_s_setprio(0);

    float* ob = out + (((long)img * H2O + py + 1) * H2O + (px + 1)) * COUT;
    #pragma unroll
    for (int g = 0; g < 4; ++g) {
        int co = ntb * 32 + g * 8 + 4 * hi;
        float v0 = acc[4 * g + 0] + shp[co + 0];
        float v1 = acc[4 * g + 1] + shp[co + 1];
        float v2 = acc[4 * g + 2] + shp[co + 2];
        float v3 = acc[4 * g + 3] + shp[co + 3];
        *(float4*)(ob + co) = make_float4(fmaxf(v0, 0.f), fmaxf(v1, 0.f),
                                          fmaxf(v2, 0.f), fmaxf(v3, 0.f));
    }
}

// --- block_fused: whole residual pair, one image per block ------------------
template<int CIN, int HIN, int TPW, int BLK>
__global__ __launch_bounds__(BLK) void block_fused(
        const float* __restrict__ in, const ushort_t* __restrict__ wf1,
        const ushort_t* __restrict__ wf2, const float* __restrict__ sh1,
        const float* __restrict__ sh2, float* __restrict__ out) {
    constexpr int H2 = HIN + 2, H2PIX = H2 * H2;
    constexpr int C8 = CIN / 8;
    constexpr int NKS = 5 * C8;
    constexpr int CHUNK = 5, NC = NKS / CHUNK;
    constexpr int NTT = CIN / 32;
    constexpr int BUFU = 3 * C8 * H2PIX;

    __shared__ uint4 lds[BUFU];
    ushort_t* lsh = (ushort_t*)lds;

    int tid = threadIdx.x, lane = tid & 63, wid = tid >> 6;
    int lp = lane & 31, hi = lane >> 5;
    int img = swz_bid();

    int ntb0 = (wid * TPW) % NTT;
    int pb[TPW];
    #pragma unroll
    for (int t = 0; t < TPW; ++t) {
        int tl = wid * TPW + t;
        int pix = (tl / NTT) * 32 + lp;
        pb[t] = (pix / HIN + 1) * H2 + (pix % HIN + 1);
    }

    const float* ib = in + (long)img * H2PIX * CIN;
    for (int it = tid; it < H2PIX * C8; it += BLK) {
        int cc = it % C8, pix = it / C8;
        const float4* p4 = (const float4*)(ib + (long)pix * CIN + cc * 8);
        float4 a0 = p4[0], a1 = p4[1];
        float vv[8] = {a0.x, a0.y, a0.z, a0.w, a1.x, a1.y, a1.z, a1.w};
        union { ushort_t u[8]; uint4 q; } H, M, L;
        #pragma unroll
        for (int q = 0; q < 8; ++q) split3(vv[q], H.u[q], M.u[q], L.u[q]);
        lds[(cc * 3 + 0) * H2PIX + pix] = H.q;
        lds[(cc * 3 + 1) * H2PIX + pix] = M.q;
        lds[(cc * 3 + 2) * H2PIX + pix] = L.q;
    }
    __syncthreads();

    bf16x8 wA[CHUNK][3], wB[CHUNK][3];
    f32x16 acc[TPW];

    auto CONV = [&](const ushort_t* wf) {
        const ushort_t* wfl = wf + lane * 8;
        #pragma unroll
        for (int t = 0; t < TPW; ++t)
            #pragma unroll
            for (int q = 0; q < 16; ++q) acc[t][q] = 0.f;
        auto LW = [&](int c, bf16x8 (&w)[CHUNK][3]) {
            #pragma unroll
            for (int i = 0; i < CHUNK; ++i) {
                int ks = c * CHUNK + i;
                #pragma unroll
                for (int pp = 0; pp < 3; ++pp)
                    w[i][pp] = *(const bf16x8*)(wfl + ((ks * NTT + ntb0) * 3 + pp) * 512);
            }
        };
        auto DOC = [&](int c, bf16x8 (&w)[CHUNK][3]) {
            #pragma unroll
            for (int i = 0; i < CHUNK; ++i) {
                int ks = c * CHUNK + i;
                int o = 2 * ks + hi;
                int tap = o % 10, c8i = o / 10;
                int ky = (tap * 11) >> 5, kx = tap - 3 * ky;
                int rel = (tap == 9) ? 0 : (ky - 1) * H2 + (kx - 1);
                #pragma unroll
                for (int t = 0; t < TPW; ++t) {
                    int a = (tap == 9) ? (c8i * 3) * H2PIX
                                       : (c8i * 3) * H2PIX + pb[t] + rel;
                    bf16x8 x0 = *(const bf16x8*)&lds[a];
                    bf16x8 x1 = *(const bf16x8*)&lds[a + H2PIX];
                    bf16x8 x2 = *(const bf16x8*)&lds[a + 2 * H2PIX];
                    f32x16 c2 = acc[t];
                    c2 = __builtin_amdgcn_mfma_f32_32x32x16_bf16(w[i][0], x0, c2, 0, 0, 0);
                    c2 = __builtin_amdgcn_mfma_f32_32x32x16_bf16(w[i][1], x0, c2, 0, 0, 0);
                    c2 = __builtin_amdgcn_mfma_f32_32x32x16_bf16(w[i][0], x1, c2, 0, 0, 0);
                    c2 = __builtin_amdgcn_mfma_f32_32x32x16_bf16(w[i][2], x0, c2, 0, 0, 0);
                    c2 = __builtin_amdgcn_mfma_f32_32x32x16_bf16(w[i][1], x1, c2, 0, 0, 0);
                    c2 = __builtin_amdgcn_mfma_f32_32x32x16_bf16(w[i][0], x2, c2, 0, 0, 0);
                    acc[t] = c2;
                }
            }
        };
        LW(0, wA);
        if (NC > 1) LW(1, wB);
        __builtin_amdgcn_s_setprio(1);
        #pragma unroll 1
        for (int c = 0; c < NC; c += 2) {
            DOC(c, wA);
            if (c + 2 < NC) LW(c + 2, wA);
            if (c + 1 < NC) { DOC(c + 1, wB); if (c + 3 < NC) LW(c + 3, wB); }
        }
        __builtin_amdgcn_s_setprio(0);
    };

    CONV(wf1);
    __syncthreads();
    #pragma unroll
    for (int t = 0; t < TPW; ++t) {
        #pragma unroll
        for (int q = 0; q < 4; ++q) {
            int co = ntb0 * 32 + q * 8 + 4 * hi;
            int c8o = co >> 3;
            ushort4 h4, m4, l4;
            #pragma unroll
            for (int e = 0; e < 4; ++e) {
                float val = fmaxf(acc[t][4 * q + e] + sh1[co + e], 0.f);
                ushort_t h, m2, l;
                split3(val, h, m2, l);
                ((ushort_t*)&h4)[e] = h; ((ushort_t*)&m4)[e] = m2; ((ushort_t*)&l4)[e] = l;
            }
            int so = (((c8o * 3) * H2PIX + pb[t]) << 3) + (co & 7);
            *(ushort4*)&lsh[so] = h4;
            *(ushort4*)&lsh[so + H2PIX * 8] = m4;
            *(ushort4*)&lsh[so + 2 * H2PIX * 8] = l4;
        }
    }
    __syncthreads();

    CONV(wf2);
    float* ob = out + (long)img * H2PIX * CIN;
    #pragma unroll
    for (int t = 0; t < TPW; ++t) {
        #pragma unroll
        for (int q = 0; q < 4; ++q) {
            int co = ntb0 * 32 + q * 8 + 4 * hi;
            float4 r = *(const float4*)(ib + (long)pb[t] * CIN + co);
            float v0 = acc[t][4 * q + 0] + sh2[co + 0] + r.x;
            float v1 = acc[t][4 * q + 1] + sh2[co + 1] + r.y;
            float v2 = acc[t][4 * q + 2] + sh2[co + 2] + r.z;
            float v3 = acc[t][4 * q + 3] + sh2[co + 3] + r.w;
            *(float4*)(ob + (long)pb[t] * CIN + co) =
                make_float4(fmaxf(v0, 0.f), fmaxf(v1, 0.f), fmaxf(v2, 0.f), fmaxf(v3, 0.f));
        }
    }
}

// --- avgpool (8x8, padded fp32 10x10x64) + FC (64->10) ----------------------
__global__ void pool_fc(const float* __restrict__ X, const float* __restrict__ fw,
                        const float* __restrict__ fb, float* __restrict__ out) {
    int b = blockIdx.x;
    int c = threadIdx.x;
    float s = 0.f;
    #pragma unroll
    for (int p = 0; p < 64; ++p) {
        int y = p >> 3, x = p & 7;
        s += X[(((long)b * 10 + y + 1) * 10 + (x + 1)) * 64 + c];
    }
    __shared__ float pooled[64];
    pooled[c] = s * (1.f / 64.f);
    __syncthreads();
    if (c < 10) {
        float acc = fb[c];
        #pragma unroll
        for (int k = 0; k < 64; ++k) acc += pooled[k] * fw[c * 64 + k];
        out[b * 10 + c] = acc;
    }
}

extern "C" void kernel_launch(void* const* d_in, const int* in_sizes, int n_in,
                              void* d_out, int out_size, void* d_ws, size_t ws_size,
                              hipStream_t stream) {
    const float* x       = (const float*)d_in[0];
    const float* conv1_w = (const float*)d_in[1];
    const float* conv1_b = (const float*)d_in[2];
    const float* bn_g    = (const float*)d_in[3];
    const float* bn_b    = (const float*)d_in[4];
    const float* bn_m    = (const float*)d_in[5];
    const float* bn_v    = (const float*)d_in[6];
    const float* hn_w2   = (const float*)d_in[7];
    const float* hn_b2   = (const float*)d_in[8];
    const float* hn_w1   = (const float*)d_in[9];
    const float* hn_b1   = (const float*)d_in[10];
    const float* z_all   = (const float*)d_in[11];
    const float* res_w6  = (const float*)d_in[12];
    const float* res_b6  = (const float*)d_in[13];
    const float* res_w12 = (const float*)d_in[14];
    const float* res_b12 = (const float*)d_in[15];
    const float* fin_w   = (const float*)d_in[16];
    const float* fin_b   = (const float*)d_in[17];
    float* outp = (float*)d_out;

    float* wsf      = (float*)d_ws;
    float* Wg       = wsf;                       // 557568 fp32
    float* bnsc     = wsf + 557568;
    float* bnsh     = wsf + 559936;
    float* shp13    = wsf + 562304;              // 32
    float* shp25    = wsf + 564864;              // 64
    ushort_t* Wfrag = (ushort_t*)(wsf + 565248); // 1866240 shorts

    float* A0f = (float*)((char*)d_ws + (size_t)(16) * (1 << 20));
    float* A1f = (float*)((char*)d_ws + (size_t)(80) * (1 << 20));
    float* A2f = (float*)((char*)d_ws + (size_t)(144) * (1 << 20));

    static const int wfoff[36] = WFOFF_LIST;

    prep<<<20, 256, 0, stream>>>(bn_g, bn_b, bn_m, bn_v, res_b6, res_b12,
                                 bnsc, bnsh, shp13, shp25);
    hyper_kernel<<<242, 256, 0, stream>>>(z_all, hn_w2, hn_b2, hn_w1, hn_b1, bnsc, Wg);
    split_w<<<dim3(168, 36), 256, 0, stream>>>(Wg, res_w6, res_w12, Wfrag);
    conv_first<<<4096, 256, 0, stream>>>(x, conv1_w, conv1_b, bn_g, bn_b, bn_m, bn_v, A0f);

    // ---- stage 1: unfused conv_s1 pairs (unpadded 32x32x16) ----
    float* X = A0f; float* T1 = A1f; float* T2 = A2f;
    for (int i = 0; i < 6; ++i) {
        int L1 = 2 * i, L2 = 2 * i + 1;
        conv_s1<0><<<4096, 256, 0, stream>>>(
            X, Wfrag + wfoff[L1], bnsh + (L1 + 1) * 64, nullptr, T1);
        conv_s1<1><<<4096, 256, 0, stream>>>(
            T1, Wfrag + wfoff[L2], bnsh + (L2 + 1) * 64, X, T2);
        float* tmp = X; X = T2; T2 = tmp;
    }
    // X = A0f.
    // ---- i = 6 transition ----
    pad_zero_f32<<<2176, 256, 0, stream>>>(A1f, 18, 8);
    conv_mfma<16,32,32,2,8,16,1><<<2048, 256, 0, stream>>>(
        A0f, Wfrag + wfoff[12], bnsh + 13 * 64, A1f);              // -> padded 18x18x32
    pad_zero_f32<<<2176, 256, 0, stream>>>(A2f, 18, 8);
    conv_s23<32,32,16,1,128,3,1,3><<<2048, 256, 0, stream>>>(
        A1f, Wfrag + wfoff[13], shp13, A0f, A2f);                  // + 1x1s2 res (k-step)

    // ---- stage 2: whole-image fused pairs, 256t TPW=2 (A2f <-> A1f) ----
    X = A2f; float* T = A1f;
    for (int i = 7; i < 12; ++i) {
        int L1 = 2 * i, L2 = 2 * i + 1;
        block_fused<32,16,2,256><<<1024, 256, 0, stream>>>(
            X, Wfrag + wfoff[L1], Wfrag + wfoff[L2],
            bnsh + (L1 + 1) * 64, bnsh + (L2 + 1) * 64, T);
        float* tmp = X; X = T; T = tmp;
    }
    // X = A1f (padded 18x18x32).
    // ---- i = 12 transition ----
    pad_zero_f32<<<2304, 256, 0, stream>>>(A0f, 10, 16);
    conv_s23<32,64,16,2,64,0,0,5><<<1024, 256, 0, stream>>>(
        A1f, Wfrag + wfoff[24], bnsh + 25 * 64, nullptr, A0f);     // -> padded 10x10x64
    pad_zero_f32<<<2304, 256, 0, stream>>>(A2f, 10, 16);
    conv_s23<64,64,8,1,64,2,2,6><<<1024, 256, 0, stream>>>(
        A0f, Wfrag + wfoff[25], shp25, A1f, A2f);                  // + 1x1s2 res (k-steps)

    // ---- stage 3: whole-image fused pairs, 256t TPW=1 (A2f <-> A0f) ----
    X = A2f; T = A0f;
    for (int i = 13; i < 18; ++i) {
        int L1 = 2 * i, L2 = 2 * i + 1;
        block_fused<64,8,1,256><<<1024, 256, 0, stream>>>(
            X, Wfrag + wfoff[L1], Wfrag + wfoff[L2],
            bnsh + (L1 + 1) * 64, bnsh + (L2 + 1) * 64, T);
        float* tmp = X; X = T; T = tmp;
    }
    // X = A0f.
    pool_fc<<<1024, 64, 0, stream>>>(A0f, fin_w, fin_b, outp);
}